// Round 6
// baseline (326.787 us; speedup 1.0000x reference)
//
#include <hip/hip_runtime.h>
#include <math.h>

// MaskedAttention B=16 T=2048 C=1024 D=64 — bf16 MFMA, compensated numerics.
// R5: proj 1024x32-row blocks (grid was occupancy cap at 2 blocks/CU);
//     attn drops K/V LDS staging (L2-resident, m169) -> barrier-free waves,
//     statically balanced light/heavy q-tile pairing, reg double-buffered K.

#define B_ 16
#define T_ 2048
#define C_ 1024
#define D_ 64
#define BT_ (B_ * T_)

typedef __attribute__((ext_vector_type(8))) short short8;
typedef __attribute__((ext_vector_type(4))) float f32x4;

__device__ __forceinline__ unsigned short f2bf(float f) {
    unsigned u = __float_as_uint(f);
    return (unsigned short)((u + 0x7fffu + ((u >> 16) & 1u)) >> 16);
}
__device__ __forceinline__ float bf2f(unsigned short h) {
    return __uint_as_float(((unsigned)h) << 16);
}
#define MFMA16(a, b, c) __builtin_amdgcn_mfma_f32_16x16x32_bf16((a), (b), (c), 0, 0, 0)

// ------------------------------------------------------------------ W prep
// Coalesced transpose via LDS. 48 blocks: (wi = which W, ct = 64-wide c tile).
__global__ __launch_bounds__(256) void wprep_kernel(
    const float* __restrict__ Wq, const float* __restrict__ Wk,
    const float* __restrict__ Wv, short* __restrict__ WTh, short* __restrict__ WTl)
{
    __shared__ float ws[64][65];
    const int bid = blockIdx.x, tid = threadIdx.x;
    const int wi = bid >> 4, ct = bid & 15, c0 = ct * 64;
    const float* W = (wi == 0) ? Wq : (wi == 1) ? Wk : Wv;
    #pragma unroll
    for (int i = 0; i < 4; ++i) {
        int rr = (tid >> 4) + i * 16;
        int dd = (tid & 15) * 4;
        *(float4*)&ws[rr][dd] = *(const float4*)&W[(size_t)(c0 + rr) * 64 + dd];
    }
    __syncthreads();
    const int d = tid >> 2, cc0 = (tid & 3) * 16;
    short8 h0, h1, l0, l1;
    #pragma unroll
    for (int i = 0; i < 8; ++i) {
        float v = ws[cc0 + i][d];
        unsigned short hh = f2bf(v);
        h0[i] = (short)hh; l0[i] = (short)f2bf(v - bf2f(hh));
        float v2 = ws[cc0 + 8 + i][d];
        unsigned short hh2 = f2bf(v2);
        h1[i] = (short)hh2; l1[i] = (short)f2bf(v2 - bf2f(hh2));
    }
    size_t o = (size_t)(wi * 64 + d) * 1024 + c0 + cc0;
    *(short8*)&WTh[o] = h0; *(short8*)&WTh[o + 8] = h1;
    *(short8*)&WTl[o] = l0; *(short8*)&WTl[o + 8] = l1;
}

// ------------------------------------------------------------------ projection
// 1024 blocks x 256 thr. Block = 32 rows (4 blocks/CU). Wave w: cols 48w..48w+47.
__global__ __launch_bounds__(256) void qkv_mfma_kernel(
    const float* __restrict__ x, const short* __restrict__ WTh,
    const short* __restrict__ WTl, float* __restrict__ qf,
    short* __restrict__ kbf, short* __restrict__ vtb)
{
    __shared__ alignas(16) short xh[32 * 64];   // [row][64], 16B units XOR-swizzled
    __shared__ alignas(16) short xl[32 * 64];

    const int tid = threadIdx.x;
    const int row0 = blockIdx.x * 32;
    const int lane = tid & 63, w = tid >> 6;
    const int lr = lane & 15, lg = lane >> 4;
    const int sr = tid >> 3, sc = (tid & 7) * 8;   // staging: row sr, cols sc..sc+7

    f32x4 acc[2][3];
    #pragma unroll
    for (int mt = 0; mt < 2; ++mt)
        #pragma unroll
        for (int gi = 0; gi < 3; ++gi) acc[mt][gi] = (f32x4){0.f, 0.f, 0.f, 0.f};

    for (int kb = 0; kb < C_; kb += 64) {
        float xv[8];
        const float* xp = &x[(size_t)(row0 + sr) * C_ + kb + sc];
        *(float4*)&xv[0] = *(const float4*)&xp[0];
        *(float4*)&xv[4] = *(const float4*)&xp[4];
        short8 h0, l0;
        #pragma unroll
        for (int i = 0; i < 8; ++i) {
            unsigned short hh = f2bf(xv[i]);
            h0[i] = (short)hh; l0[i] = (short)f2bf(xv[i] - bf2f(hh));
        }
        __syncthreads();   // prior iteration's reads complete
        {
            int u0 = (sc >> 3) ^ (sr & 7);
            *(short8*)&xh[sr * 64 + u0 * 8] = h0;
            *(short8*)&xl[sr * 64 + u0 * 8] = l0;
        }
        __syncthreads();

        #pragma unroll
        for (int kc = 0; kc < 2; ++kc) {
            short8 ah[2], al[2];
            #pragma unroll
            for (int mt = 0; mt < 2; ++mt) {
                int r = mt * 16 + lr;
                int usw = (kc * 4 + lg) ^ (r & 7);
                ah[mt] = *(short8*)&xh[r * 64 + usw * 8];
                al[mt] = *(short8*)&xl[r * 64 + usw * 8];
            }
            #pragma unroll
            for (int gi = 0; gi < 3; ++gi) {
                int n = (3 * w + gi) * 16 + lr;
                size_t wo = (size_t)n * 1024 + kb + kc * 32 + lg * 8;
                short8 wh = *(const short8*)&WTh[wo];
                short8 wl = *(const short8*)&WTl[wo];
                #pragma unroll
                for (int mt = 0; mt < 2; ++mt) {
                    acc[mt][gi] = MFMA16(ah[mt], wh, acc[mt][gi]);
                    acc[mt][gi] = MFMA16(ah[mt], wl, acc[mt][gi]);
                    acc[mt][gi] = MFMA16(al[mt], wh, acc[mt][gi]);
                }
            }
        }
    }

    // epilogue: cols 0-63 -> q (f32), 64-127 -> k (bf16), 128-191 -> v^T (bf16)
    #pragma unroll
    for (int mt = 0; mt < 2; ++mt) {
        int rbase = row0 + mt * 16 + lg * 4;
        #pragma unroll
        for (int gi = 0; gi < 3; ++gi) {
            int g = 3 * w + gi;
            f32x4 a = acc[mt][gi];
            int col = g * 16 + lr;
            if (g < 4) {
                #pragma unroll
                for (int reg = 0; reg < 4; ++reg)
                    qf[(size_t)(rbase + reg) * 64 + col] = a[reg];
            } else if (g < 8) {
                #pragma unroll
                for (int reg = 0; reg < 4; ++reg)
                    kbf[(size_t)(rbase + reg) * 64 + (col - 64)] = (short)f2bf(a[reg]);
            } else {
                int d = col - 128;
                int bb = rbase >> 11, t0 = rbase & (T_ - 1);
                short4 pk;
                pk.x = (short)f2bf(a[0]); pk.y = (short)f2bf(a[1]);
                pk.z = (short)f2bf(a[2]); pk.w = (short)f2bf(a[3]);
                *(short4*)&vtb[((size_t)(bb * 64 + d) << 11) + t0] = pk;
            }
        }
    }
}

// ------------------------------------------------------------------ attention
// 512 blocks x 256 thr; waves barrier-free. Wave = one 16-row q-tile, K/V frags
// read straight from L2. Static balance: block waves = {light, heavy} pairs,
// role-swapped on bid>=256 so co-resident blocks mix light+heavy per SIMD.
__global__ __launch_bounds__(256) void attn_mfma_kernel(
    const float* __restrict__ qf, const short* __restrict__ kbf,
    const short* __restrict__ vtb, float* __restrict__ out)
{
    __shared__ alignas(16) short pbuf[4 * 16 * 64];   // per-wave P [16][64], swizzled

    const int bid = blockIdx.x;
    const int b  = bid & 15;
    const int pp = (bid >> 4) & 31;
    const int sw = (bid >> 8) & 1;
    const int tid = threadIdx.x;
    const int lane = tid & 63, w = tid >> 6;
    const int lr = lane & 15, lg = lane >> 4;

    const int sel = w >> 1;                // pair A / pair B
    const int hv  = (w & 1) ^ sw;          // heavy role?
    const int t   = hv ? (127 - 2 * pp - sel) : (2 * pp + sel);  // 16-row q-tile
    const int trow0 = t * 16;
    const int njt = (t >> 2) + 1;          // 64-wide j-tiles needed

    const size_t base_tok = (size_t)b * T_;
    const short* Kb = kbf + base_tok * 64;          // [t][64]
    const short* Vb = vtb + (size_t)b * 64 * T_;    // [d][T]
    short* pw = pbuf + w * 16 * 64;                 // wave-private

    // Q fragments, scaled by 1/sqrt(C)=1/32 (exact pow2), split hi/lo
    short8 qh[2], ql[2];
    #pragma unroll
    for (int kc = 0; kc < 2; ++kc) {
        const float* qp = &qf[(base_tok + trow0 + lr) * 64 + kc * 32 + lg * 8];
        float4 q0 = *(const float4*)qp;
        float4 q1 = *(const float4*)(qp + 4);
        float qs[8] = {q0.x, q0.y, q0.z, q0.w, q1.x, q1.y, q1.z, q1.w};
        #pragma unroll
        for (int i = 0; i < 8; ++i) {
            float v = qs[i] * 0.03125f;
            unsigned short hh = f2bf(v);
            qh[kc][i] = (short)hh;
            ql[kc][i] = (short)f2bf(v - bf2f(hh));
        }
    }

    f32x4 o[4];
    #pragma unroll
    for (int dt = 0; dt < 4; ++dt) o[dt] = (f32x4){0.f, 0.f, 0.f, 0.f};
    float m[4]    = {-INFINITY, -INFINITY, -INFINITY, -INFINITY};
    float lsum[4] = {0.f, 0.f, 0.f, 0.f};

    short8 kfA[2][4], kfB[2][4];
    auto loadK = [&](short8 (&kf)[2][4], int jt) {
        int j0 = jt * 64;
        #pragma unroll
        for (int kc = 0; kc < 2; ++kc)
            #pragma unroll
            for (int nt = 0; nt < 4; ++nt)
                kf[kc][nt] = *(const short8*)
                    &Kb[(size_t)(j0 + nt * 16 + lr) * 64 + kc * 32 + lg * 8];
    };

    auto doTile = [&](short8 (&kf)[2][4], short8 (&kfn)[2][4], int jt) {
        // ---- QK^T: S[16q][64j], split-Q compensated
        f32x4 sx[4];
        #pragma unroll
        for (int nt = 0; nt < 4; ++nt) sx[nt] = (f32x4){0.f, 0.f, 0.f, 0.f};
        #pragma unroll
        for (int kc = 0; kc < 2; ++kc)
            #pragma unroll
            for (int nt = 0; nt < 4; ++nt) {
                sx[nt] = MFMA16(qh[kc], kf[kc][nt], sx[nt]);
                sx[nt] = MFMA16(ql[kc], kf[kc][nt], sx[nt]);
            }

        const int j0 = jt * 64;
        // ---- V fragments (used after softmax: latency hidden under it)
        short8 vf[4][2];
        #pragma unroll
        for (int dt = 0; dt < 4; ++dt)
            #pragma unroll
            for (int kc = 0; kc < 2; ++kc)
                vf[dt][kc] = *(const short8*)
                    &Vb[(size_t)(dt * 16 + lr) * T_ + j0 + kc * 32 + lg * 8];
        // ---- prefetch next K tile (issued after V: V-wait stays counted)
        if (jt + 1 < njt) loadK(kfn, jt + 1);

        // ---- causal mask (last tile only)
        if (jt == njt - 1) {
            #pragma unroll
            for (int nt = 0; nt < 4; ++nt) {
                int j = j0 + nt * 16 + lr;
                #pragma unroll
                for (int reg = 0; reg < 4; ++reg)
                    if (j > trow0 + lg * 4 + reg) sx[nt][reg] = -INFINITY;
            }
        }

        // ---- online softmax (rows = lg*4+reg, reduce over 16 lr lanes)
        float corr[4], psum[4] = {0.f, 0.f, 0.f, 0.f};
        #pragma unroll
        for (int reg = 0; reg < 4; ++reg) {
            float vmax = fmaxf(fmaxf(sx[0][reg], sx[1][reg]),
                               fmaxf(sx[2][reg], sx[3][reg]));
            vmax = fmaxf(vmax, __shfl_xor(vmax, 1));
            vmax = fmaxf(vmax, __shfl_xor(vmax, 2));
            vmax = fmaxf(vmax, __shfl_xor(vmax, 4));
            vmax = fmaxf(vmax, __shfl_xor(vmax, 8));
            float mnew = fmaxf(m[reg], vmax);
            corr[reg] = __expf(m[reg] - mnew);
            m[reg] = mnew;
        }
        #pragma unroll
        for (int nt = 0; nt < 4; ++nt)
            #pragma unroll
            for (int reg = 0; reg < 4; ++reg) {
                float p = __expf(sx[nt][reg] - m[reg]);
                psum[reg] += p;
                int qr = lg * 4 + reg;
                int colj = nt * 16 + lr;
                int usw = (colj >> 3) ^ (qr & 7);
                pw[qr * 64 + usw * 8 + (colj & 7)] = (short)f2bf(p);
            }
        #pragma unroll
        for (int reg = 0; reg < 4; ++reg)
            lsum[reg] = lsum[reg] * corr[reg] + psum[reg];
        #pragma unroll
        for (int dt = 0; dt < 4; ++dt) {
            o[dt][0] *= corr[0]; o[dt][1] *= corr[1];
            o[dt][2] *= corr[2]; o[dt][3] *= corr[3];
        }

        // ---- PV: O += P[16x64] * V[64x64]
        asm volatile("s_waitcnt lgkmcnt(0)" ::: "memory");
        __builtin_amdgcn_sched_barrier(0);
        short8 pf[2];
        #pragma unroll
        for (int kc = 0; kc < 2; ++kc) {
            int usw = (kc * 4 + lg) ^ (lr & 7);
            pf[kc] = *(short8*)&pw[lr * 64 + usw * 8];
        }
        #pragma unroll
        for (int dt = 0; dt < 4; ++dt)
            #pragma unroll
            for (int kc = 0; kc < 2; ++kc)
                o[dt] = MFMA16(pf[kc], vf[dt][kc], o[dt]);
    };

    loadK(kfA, 0);
    int jt = 0;
    while (true) {
        doTile(kfA, kfB, jt);
        if (++jt == njt) break;
        doTile(kfB, kfA, jt);
        if (++jt == njt) break;
    }

    // ---- epilogue: row-sum reduce, normalize, store f32
    #pragma unroll
    for (int reg = 0; reg < 4; ++reg) {
        lsum[reg] += __shfl_xor(lsum[reg], 1);
        lsum[reg] += __shfl_xor(lsum[reg], 2);
        lsum[reg] += __shfl_xor(lsum[reg], 4);
        lsum[reg] += __shfl_xor(lsum[reg], 8);
        lsum[reg] = 1.f / lsum[reg];
    }
    #pragma unroll
    for (int dt = 0; dt < 4; ++dt)
        #pragma unroll
        for (int reg = 0; reg < 4; ++reg)
            out[(base_tok + trow0 + lg * 4 + reg) * 64 + dt * 16 + lr] =
                o[dt][reg] * lsum[reg];
}

// ------------------------------------------------------------------ launch
extern "C" void kernel_launch(void* const* d_in, const int* in_sizes, int n_in,
                              void* d_out, int out_size, void* d_ws, size_t ws_size,
                              hipStream_t stream) {
    const float* x  = (const float*)d_in[0];
    const float* Wq = (const float*)d_in[1];
    const float* Wk = (const float*)d_in[2];
    const float* Wv = (const float*)d_in[3];
    float* out = (float*)d_out;

    // workspace: qf f32 8MB | kbf bf16 4MB | vtb bf16 4MB | WTh 384KB | WTl 384KB
    float* qf  = (float*)d_ws;
    short* kbf = (short*)(qf + (size_t)BT_ * 64);
    short* vtb = kbf + (size_t)BT_ * 64;
    short* WTh = vtb + (size_t)BT_ * 64;
    short* WTl = WTh + (size_t)192 * 1024;

    wprep_kernel<<<48, 256, 0, stream>>>(Wq, Wk, Wv, WTh, WTl);
    qkv_mfma_kernel<<<1024, 256, 0, stream>>>(x, WTh, WTl, qf, kbf, vtb);
    attn_mfma_kernel<<<512, 256, 0, stream>>>(qf, kbf, vtb, out);
}

// Round 9
// 297.444 us; speedup vs baseline: 1.0987x; 1.0987x over previous
//
#include <hip/hip_runtime.h>
#include <math.h>

// MaskedAttention B=16 T=2048 C=1024 D=64 — bf16 MFMA, compensated numerics.
// R7: proj back to 64-row/512-block (R6's 32-row halved compute-per-W-load and
//     regressed); added 1-barrier double-buffered x pipeline (prefetch 2 ahead)
//     + hoisted W loads. attn unchanged from R6 (barrier-free, L2-direct K/V).

#define B_ 16
#define T_ 2048
#define C_ 1024
#define D_ 64
#define BT_ (B_ * T_)

typedef __attribute__((ext_vector_type(8))) short short8;
typedef __attribute__((ext_vector_type(4))) float f32x4;

__device__ __forceinline__ unsigned short f2bf(float f) {
    unsigned u = __float_as_uint(f);
    return (unsigned short)((u + 0x7fffu + ((u >> 16) & 1u)) >> 16);
}
__device__ __forceinline__ float bf2f(unsigned short h) {
    return __uint_as_float(((unsigned)h) << 16);
}
#define MFMA16(a, b, c) __builtin_amdgcn_mfma_f32_16x16x32_bf16((a), (b), (c), 0, 0, 0)

// ------------------------------------------------------------------ W prep
// Coalesced transpose via LDS. 48 blocks: (wi = which W, ct = 64-wide c tile).
__global__ __launch_bounds__(256) void wprep_kernel(
    const float* __restrict__ Wq, const float* __restrict__ Wk,
    const float* __restrict__ Wv, short* __restrict__ WTh, short* __restrict__ WTl)
{
    __shared__ float ws[64][65];
    const int bid = blockIdx.x, tid = threadIdx.x;
    const int wi = bid >> 4, ct = bid & 15, c0 = ct * 64;
    const float* W = (wi == 0) ? Wq : (wi == 1) ? Wk : Wv;
    #pragma unroll
    for (int i = 0; i < 4; ++i) {
        int rr = (tid >> 4) + i * 16;
        int dd = (tid & 15) * 4;
        *(float4*)&ws[rr][dd] = *(const float4*)&W[(size_t)(c0 + rr) * 64 + dd];
    }
    __syncthreads();
    const int d = tid >> 2, cc0 = (tid & 3) * 16;
    short8 h0, h1, l0, l1;
    #pragma unroll
    for (int i = 0; i < 8; ++i) {
        float v = ws[cc0 + i][d];
        unsigned short hh = f2bf(v);
        h0[i] = (short)hh; l0[i] = (short)f2bf(v - bf2f(hh));
        float v2 = ws[cc0 + 8 + i][d];
        unsigned short hh2 = f2bf(v2);
        h1[i] = (short)hh2; l1[i] = (short)f2bf(v2 - bf2f(hh2));
    }
    size_t o = (size_t)(wi * 64 + d) * 1024 + c0 + cc0;
    *(short8*)&WTh[o] = h0; *(short8*)&WTh[o + 8] = h1;
    *(short8*)&WTl[o] = l0; *(short8*)&WTl[o + 8] = l1;
}

// ------------------------------------------------------------------ projection
// 512 blocks x 256 thr. Block = 64 rows. Wave w: output cols 48w..48w+47.
// Double-buffered x LDS, one barrier per k-step, x loads issued 2 steps ahead.
__global__ __launch_bounds__(256) void qkv_mfma_kernel(
    const float* __restrict__ x, const short* __restrict__ WTh,
    const short* __restrict__ WTl, float* __restrict__ qf,
    short* __restrict__ kbf, short* __restrict__ vtb)
{
    __shared__ alignas(16) short xh[2][64 * 64];   // [buf][row][64], XOR-swizzled units
    __shared__ alignas(16) short xl[2][64 * 64];

    const int tid = threadIdx.x;
    const int row0 = blockIdx.x * 64;
    const int lane = tid & 63, w = tid >> 6;
    const int lr = lane & 15, lg = lane >> 4;
    const int sr = tid >> 2, sc = (tid & 3) * 16;   // staging: row sr, cols sc..sc+15

    f32x4 acc[4][3];
    #pragma unroll
    for (int mt = 0; mt < 4; ++mt)
        #pragma unroll
        for (int gi = 0; gi < 3; ++gi) acc[mt][gi] = (f32x4){0.f, 0.f, 0.f, 0.f};

    const float* xrow = &x[(size_t)(row0 + sr) * C_ + sc];

    float xv[16];
    auto issue_loads = [&](int kb) {
        *(float4*)&xv[0]  = *(const float4*)&xrow[kb];
        *(float4*)&xv[4]  = *(const float4*)&xrow[kb + 4];
        *(float4*)&xv[8]  = *(const float4*)&xrow[kb + 8];
        *(float4*)&xv[12] = *(const float4*)&xrow[kb + 12];
    };
    auto convert_write = [&](int buf) {
        short8 h0, h1, l0, l1;
        #pragma unroll
        for (int i = 0; i < 8; ++i) {
            unsigned short hh = f2bf(xv[i]);
            h0[i] = (short)hh; l0[i] = (short)f2bf(xv[i] - bf2f(hh));
            unsigned short hh2 = f2bf(xv[8 + i]);
            h1[i] = (short)hh2; l1[i] = (short)f2bf(xv[8 + i] - bf2f(hh2));
        }
        int u0 = sc >> 3, u1 = u0 + 1;
        *(short8*)&xh[buf][sr * 64 + ((u0 ^ (sr & 7)) * 8)] = h0;
        *(short8*)&xh[buf][sr * 64 + ((u1 ^ (sr & 7)) * 8)] = h1;
        *(short8*)&xl[buf][sr * 64 + ((u0 ^ (sr & 7)) * 8)] = l0;
        *(short8*)&xl[buf][sr * 64 + ((u1 ^ (sr & 7)) * 8)] = l1;
    };

    issue_loads(0);
    convert_write(0);        // buf0 = k-step 0
    issue_loads(64);         // regs = k-step 1

    for (int t = 0; t < 16; ++t) {
        __syncthreads();     // buf[t&1] writes visible; prior reads of buf[(t+1)&1] done
        if (t < 15) convert_write((t + 1) & 1);   // consumes regs (k-step t+1)
        if (t < 14) issue_loads((t + 2) * 64);    // regs = k-step t+2

        const int kb = t * 64;
        const int bsel = t & 1;

        // hoist all 12 W slab loads (L2) ahead of LDS reads + MFMA
        short8 wfh[2][3], wfl[2][3];
        #pragma unroll
        for (int kc = 0; kc < 2; ++kc)
            #pragma unroll
            for (int gi = 0; gi < 3; ++gi) {
                int n = (3 * w + gi) * 16 + lr;
                size_t wo = (size_t)n * 1024 + kb + kc * 32 + lg * 8;
                wfh[kc][gi] = *(const short8*)&WTh[wo];
                wfl[kc][gi] = *(const short8*)&WTl[wo];
            }

        #pragma unroll
        for (int kc = 0; kc < 2; ++kc) {
            short8 ah[4], al[4];
            #pragma unroll
            for (int mt = 0; mt < 4; ++mt) {
                int r = mt * 16 + lr;
                int usw = (kc * 4 + lg) ^ (r & 7);
                ah[mt] = *(short8*)&xh[bsel][r * 64 + usw * 8];
                al[mt] = *(short8*)&xl[bsel][r * 64 + usw * 8];
            }
            #pragma unroll
            for (int gi = 0; gi < 3; ++gi)
                #pragma unroll
                for (int mt = 0; mt < 4; ++mt) {
                    acc[mt][gi] = MFMA16(ah[mt], wfh[kc][gi], acc[mt][gi]);
                    acc[mt][gi] = MFMA16(ah[mt], wfl[kc][gi], acc[mt][gi]);
                    acc[mt][gi] = MFMA16(al[mt], wfh[kc][gi], acc[mt][gi]);
                }
        }
    }

    // epilogue: cols 0-63 -> q (f32), 64-127 -> k (bf16), 128-191 -> v^T (bf16)
    #pragma unroll
    for (int mt = 0; mt < 4; ++mt) {
        int rbase = row0 + mt * 16 + lg * 4;
        #pragma unroll
        for (int gi = 0; gi < 3; ++gi) {
            int g = 3 * w + gi;
            f32x4 a = acc[mt][gi];
            int col = g * 16 + lr;
            if (g < 4) {
                #pragma unroll
                for (int reg = 0; reg < 4; ++reg)
                    qf[(size_t)(rbase + reg) * 64 + col] = a[reg];
            } else if (g < 8) {
                #pragma unroll
                for (int reg = 0; reg < 4; ++reg)
                    kbf[(size_t)(rbase + reg) * 64 + (col - 64)] = (short)f2bf(a[reg]);
            } else {
                int d = col - 128;
                int bb = rbase >> 11, t0 = rbase & (T_ - 1);
                short4 pk;
                pk.x = (short)f2bf(a[0]); pk.y = (short)f2bf(a[1]);
                pk.z = (short)f2bf(a[2]); pk.w = (short)f2bf(a[3]);
                *(short4*)&vtb[((size_t)(bb * 64 + d) << 11) + t0] = pk;
            }
        }
    }
}

// ------------------------------------------------------------------ attention
// 512 blocks x 256 thr; waves barrier-free. Wave = one 16-row q-tile, K/V frags
// read straight from L2. Static balance: block waves = {light, heavy} pairs,
// role-swapped on bid>=256 so co-resident blocks mix light+heavy per SIMD.
__global__ __launch_bounds__(256) void attn_mfma_kernel(
    const float* __restrict__ qf, const short* __restrict__ kbf,
    const short* __restrict__ vtb, float* __restrict__ out)
{
    __shared__ alignas(16) short pbuf[4 * 16 * 64];   // per-wave P [16][64], swizzled

    const int bid = blockIdx.x;
    const int b  = bid & 15;
    const int pp = (bid >> 4) & 31;
    const int sw = (bid >> 8) & 1;
    const int tid = threadIdx.x;
    const int lane = tid & 63, w = tid >> 6;
    const int lr = lane & 15, lg = lane >> 4;

    const int sel = w >> 1;                // pair A / pair B
    const int hv  = (w & 1) ^ sw;          // heavy role?
    const int t   = hv ? (127 - 2 * pp - sel) : (2 * pp + sel);  // 16-row q-tile
    const int trow0 = t * 16;
    const int njt = (t >> 2) + 1;          // 64-wide j-tiles needed

    const size_t base_tok = (size_t)b * T_;
    const short* Kb = kbf + base_tok * 64;          // [t][64]
    const short* Vb = vtb + (size_t)b * 64 * T_;    // [d][T]
    short* pw = pbuf + w * 16 * 64;                 // wave-private

    // Q fragments, scaled by 1/sqrt(C)=1/32 (exact pow2), split hi/lo
    short8 qh[2], ql[2];
    #pragma unroll
    for (int kc = 0; kc < 2; ++kc) {
        const float* qp = &qf[(base_tok + trow0 + lr) * 64 + kc * 32 + lg * 8];
        float4 q0 = *(const float4*)qp;
        float4 q1 = *(const float4*)(qp + 4);
        float qs[8] = {q0.x, q0.y, q0.z, q0.w, q1.x, q1.y, q1.z, q1.w};
        #pragma unroll
        for (int i = 0; i < 8; ++i) {
            float v = qs[i] * 0.03125f;
            unsigned short hh = f2bf(v);
            qh[kc][i] = (short)hh;
            ql[kc][i] = (short)f2bf(v - bf2f(hh));
        }
    }

    f32x4 o[4];
    #pragma unroll
    for (int dt = 0; dt < 4; ++dt) o[dt] = (f32x4){0.f, 0.f, 0.f, 0.f};
    float m[4]    = {-INFINITY, -INFINITY, -INFINITY, -INFINITY};
    float lsum[4] = {0.f, 0.f, 0.f, 0.f};

    short8 kfA[2][4], kfB[2][4];
    auto loadK = [&](short8 (&kf)[2][4], int jt) {
        int j0 = jt * 64;
        #pragma unroll
        for (int kc = 0; kc < 2; ++kc)
            #pragma unroll
            for (int nt = 0; nt < 4; ++nt)
                kf[kc][nt] = *(const short8*)
                    &Kb[(size_t)(j0 + nt * 16 + lr) * 64 + kc * 32 + lg * 8];
    };

    auto doTile = [&](short8 (&kf)[2][4], short8 (&kfn)[2][4], int jt) {
        // ---- QK^T: S[16q][64j], split-Q compensated
        f32x4 sx[4];
        #pragma unroll
        for (int nt = 0; nt < 4; ++nt) sx[nt] = (f32x4){0.f, 0.f, 0.f, 0.f};
        #pragma unroll
        for (int kc = 0; kc < 2; ++kc)
            #pragma unroll
            for (int nt = 0; nt < 4; ++nt) {
                sx[nt] = MFMA16(qh[kc], kf[kc][nt], sx[nt]);
                sx[nt] = MFMA16(ql[kc], kf[kc][nt], sx[nt]);
            }

        const int j0 = jt * 64;
        // ---- V fragments (used after softmax: latency hidden under it)
        short8 vf[4][2];
        #pragma unroll
        for (int dt = 0; dt < 4; ++dt)
            #pragma unroll
            for (int kc = 0; kc < 2; ++kc)
                vf[dt][kc] = *(const short8*)
                    &Vb[(size_t)(dt * 16 + lr) * T_ + j0 + kc * 32 + lg * 8];
        // ---- prefetch next K tile (issued after V: V-wait stays counted)
        if (jt + 1 < njt) loadK(kfn, jt + 1);

        // ---- causal mask (last tile only)
        if (jt == njt - 1) {
            #pragma unroll
            for (int nt = 0; nt < 4; ++nt) {
                int j = j0 + nt * 16 + lr;
                #pragma unroll
                for (int reg = 0; reg < 4; ++reg)
                    if (j > trow0 + lg * 4 + reg) sx[nt][reg] = -INFINITY;
            }
        }

        // ---- online softmax (rows = lg*4+reg, reduce over 16 lr lanes)
        float corr[4], psum[4] = {0.f, 0.f, 0.f, 0.f};
        #pragma unroll
        for (int reg = 0; reg < 4; ++reg) {
            float vmax = fmaxf(fmaxf(sx[0][reg], sx[1][reg]),
                               fmaxf(sx[2][reg], sx[3][reg]));
            vmax = fmaxf(vmax, __shfl_xor(vmax, 1));
            vmax = fmaxf(vmax, __shfl_xor(vmax, 2));
            vmax = fmaxf(vmax, __shfl_xor(vmax, 4));
            vmax = fmaxf(vmax, __shfl_xor(vmax, 8));
            float mnew = fmaxf(m[reg], vmax);
            corr[reg] = __expf(m[reg] - mnew);
            m[reg] = mnew;
        }
        #pragma unroll
        for (int nt = 0; nt < 4; ++nt)
            #pragma unroll
            for (int reg = 0; reg < 4; ++reg) {
                float p = __expf(sx[nt][reg] - m[reg]);
                psum[reg] += p;
                int qr = lg * 4 + reg;
                int colj = nt * 16 + lr;
                int usw = (colj >> 3) ^ (qr & 7);
                pw[qr * 64 + usw * 8 + (colj & 7)] = (short)f2bf(p);
            }
        #pragma unroll
        for (int reg = 0; reg < 4; ++reg)
            lsum[reg] = lsum[reg] * corr[reg] + psum[reg];
        #pragma unroll
        for (int dt = 0; dt < 4; ++dt) {
            o[dt][0] *= corr[0]; o[dt][1] *= corr[1];
            o[dt][2] *= corr[2]; o[dt][3] *= corr[3];
        }

        // ---- PV: O += P[16x64] * V[64x64]
        asm volatile("s_waitcnt lgkmcnt(0)" ::: "memory");
        __builtin_amdgcn_sched_barrier(0);
        short8 pf[2];
        #pragma unroll
        for (int kc = 0; kc < 2; ++kc) {
            int usw = (kc * 4 + lg) ^ (lr & 7);
            pf[kc] = *(short8*)&pw[lr * 64 + usw * 8];
        }
        #pragma unroll
        for (int dt = 0; dt < 4; ++dt)
            #pragma unroll
            for (int kc = 0; kc < 2; ++kc)
                o[dt] = MFMA16(pf[kc], vf[dt][kc], o[dt]);
    };

    loadK(kfA, 0);
    int jt = 0;
    while (true) {
        doTile(kfA, kfB, jt);
        if (++jt == njt) break;
        doTile(kfB, kfA, jt);
        if (++jt == njt) break;
    }

    // ---- epilogue: row-sum reduce, normalize, store f32
    #pragma unroll
    for (int reg = 0; reg < 4; ++reg) {
        lsum[reg] += __shfl_xor(lsum[reg], 1);
        lsum[reg] += __shfl_xor(lsum[reg], 2);
        lsum[reg] += __shfl_xor(lsum[reg], 4);
        lsum[reg] += __shfl_xor(lsum[reg], 8);
        lsum[reg] = 1.f / lsum[reg];
    }
    #pragma unroll
    for (int dt = 0; dt < 4; ++dt)
        #pragma unroll
        for (int reg = 0; reg < 4; ++reg)
            out[(base_tok + trow0 + lg * 4 + reg) * 64 + dt * 16 + lr] =
                o[dt][reg] * lsum[reg];
}

// ------------------------------------------------------------------ launch
extern "C" void kernel_launch(void* const* d_in, const int* in_sizes, int n_in,
                              void* d_out, int out_size, void* d_ws, size_t ws_size,
                              hipStream_t stream) {
    const float* x  = (const float*)d_in[0];
    const float* Wq = (const float*)d_in[1];
    const float* Wk = (const float*)d_in[2];
    const float* Wv = (const float*)d_in[3];
    float* out = (float*)d_out;

    // workspace: qf f32 8MB | kbf bf16 4MB | vtb bf16 4MB | WTh 384KB | WTl 384KB
    float* qf  = (float*)d_ws;
    short* kbf = (short*)(qf + (size_t)BT_ * 64);
    short* vtb = kbf + (size_t)BT_ * 64;
    short* WTh = vtb + (size_t)BT_ * 64;
    short* WTl = WTh + (size_t)192 * 1024;

    wprep_kernel<<<48, 256, 0, stream>>>(Wq, Wk, Wv, WTh, WTl);
    qkv_mfma_kernel<<<512, 256, 0, stream>>>(x, WTh, WTl, qf, kbf, vtb);
    attn_mfma_kernel<<<512, 256, 0, stream>>>(qf, kbf, vtb, out);
}